// Round 17
// baseline (227.463 us; speedup 1.0000x reference)
//
#include <hip/hip_runtime.h>
#include <hip/hip_fp16.h>

#define NN 10000
#define DIN 128
#define HD 64
#define HH 128          // H*HEADS
#define NE 250000
#define NP 100000

typedef _Float16 h2v __attribute__((ext_vector_type(2)));

// ---------------- CSR build ----------------

// int4-vectorized: 4 cols per thread
__global__ void count_kernel(const int* e12, const int* e21, int* cnt12, int* cnt21) {
    int t = blockIdx.x * blockDim.x + threadIdx.x;
    if (t < NE / 4) {
        int4 c = ((const int4*)(e12 + NE))[t];
        atomicAdd(&cnt12[c.x], 1); atomicAdd(&cnt12[c.y], 1);
        atomicAdd(&cnt12[c.z], 1); atomicAdd(&cnt12[c.w], 1);
    } else if (t < NE / 2) {
        int4 c = ((const int4*)(e21 + NE))[t - NE / 4];
        atomicAdd(&cnt21[c.x], 1); atomicAdd(&cnt21[c.y], 1);
        atomicAdd(&cnt21[c.z], 1); atomicAdd(&cnt21[c.w], 1);
    }
}

__global__ void scan_kernel(const int* cnt12, const int* cnt21,
                            int* ptr12, int* ptr21, int* cur12, int* cur21) {
    const int* cnt = blockIdx.x ? cnt21 : cnt12;
    int* ptr = blockIdx.x ? ptr21 : ptr12;
    int* cur = blockIdx.x ? cur21 : cur12;
    const int T = 1024, C = 10;                 // 1024*10 = 10240 >= 10000
    __shared__ int sm[1024];
    int t = threadIdx.x;
    int v[C]; int tot = 0;
    int base = t * C;
    #pragma unroll
    for (int i = 0; i < C; i++) {
        int id = base + i;
        v[i] = (id < NN) ? cnt[id] : 0;
        tot += v[i];
    }
    sm[t] = tot; __syncthreads();
    for (int off = 1; off < T; off <<= 1) {
        int x = (t >= off) ? sm[t - off] : 0;
        __syncthreads();
        sm[t] += x;
        __syncthreads();
    }
    int run = sm[t] - tot;                      // exclusive prefix
    #pragma unroll
    for (int i = 0; i < C; i++) {
        int id = base + i;
        if (id < NN) { ptr[id] = run; cur[id] = run; }
        run += v[i];
    }
    if (t == T - 1) ptr[NN] = run;
}

// writes packed (row, col) per CSR slot
__global__ void fill_kernel(const int* e12, const int* e21,
                            int* cur12, int* cur21, int2* rc12, int2* rc21) {
    int t = blockIdx.x * blockDim.x + threadIdx.x;
    if (t < NE) {
        int c = e12[NE + t];
        int p = atomicAdd(&cur12[c], 1);
        rc12[p] = make_int2(e12[t], c);
    } else if (t < 2 * NE) {
        int e = t - NE;
        int c = e21[NE + e];
        int p = atomicAdd(&cur21[c], 1);
        rc21[p] = make_int2(e21[e], c);
    }
}

// ---------------- shared device pieces ----------------

__device__ __forceinline__ float dotc(const uint4& k, const uint4& q) {
#if __has_builtin(__builtin_amdgcn_fdot2)
    const h2v* kh = (const h2v*)&k;
    const h2v* qh = (const h2v*)&q;
    float s = 0.f;
    #pragma unroll
    for (int i = 0; i < 4; i++)
        s = __builtin_amdgcn_fdot2(kh[i], qh[i], s, false);
    return s;
#else
    const __half2* kh = (const __half2*)&k;
    const __half2* qh = (const __half2*)&q;
    float s = 0.f;
    #pragma unroll
    for (int i = 0; i < 4; i++) {
        float2 a = __half22float2(kh[i]);
        float2 b = __half22float2(qh[i]);
        s += a.x * b.x + a.y * b.y;
    }
    return s;
#endif
}
__device__ __forceinline__ void acc8(const uint4& v, float e, float* acc) {
    const __half2* h = (const __half2*)&v;
    float2 f0 = __half22float2(h[0]), f1 = __half22float2(h[1]);
    float2 f2 = __half22float2(h[2]), f3 = __half22float2(h[3]);
    acc[0] += e*f0.x; acc[1] += e*f0.y; acc[2] += e*f1.x; acc[3] += e*f1.y;
    acc[4] += e*f2.x; acc[5] += e*f2.y; acc[6] += e*f3.x; acc[7] += e*f3.y;
}

// 3 K/Q/V GEMM phases over the block's 16 x-rows held in LDS (Xs, 16x64 f32).
// node type z: K,V -> rel=z ; Q -> rel=1-z. W staged in Ws (32 KB) per phase.
__device__ __forceinline__ void kqv_phases(
        int z, int l, const float* Xs, float4* Ws4, int row0, int tid,
        const float* __restrict__ Wk, const float* __restrict__ Wq,
        const float* __restrict__ Wv,
        const float* __restrict__ bk, const float* __restrict__ bq,
        const float* __restrict__ bv,
        __half* Kh, __half* Qh, __half* Vh) {
    #pragma unroll
    for (int kind = 0; kind < 3; kind++) {
        int rel = (kind == 1) ? (1 - z) : z;
        size_t wo = (size_t)(l * 2 + rel) * HD * HH;
        size_t bo = (size_t)(l * 2 + rel) * HH;
        const float4* W4 = (const float4*)((kind == 0 ? Wk : kind == 1 ? Wq : Wv) + wo);
        const float4* b4 = (const float4*)((kind == 0 ? bk : kind == 1 ? bq : bv) + bo);
        #pragma unroll
        for (int i = 0; i < 8; i++) Ws4[tid + 256 * i] = W4[tid + 256 * i];
        __syncthreads();
        int cg = tid & 31, rg = tid >> 5;       // rg 0..7, rows rg*2, rg*2+1
        float4 acc0 = b4[cg], acc1 = acc0;
        const float* a0 = &Xs[(rg * 2) * HD];
        const float* a1 = &Xs[(rg * 2 + 1) * HD];
        for (int k = 0; k < HD; k++) {
            float4 w = Ws4[k * 32 + cg];
            float v0 = a0[k], v1 = a1[k];
            acc0.x += v0 * w.x; acc0.y += v0 * w.y; acc0.z += v0 * w.z; acc0.w += v0 * w.w;
            acc1.x += v1 * w.x; acc1.y += v1 * w.y; acc1.z += v1 * w.z; acc1.w += v1 * w.w;
        }
        __half* dst = (kind == 0) ? Kh : (kind == 1) ? Qh : Vh;
        int node = row0 + rg * 2;
        {
            __half2* H2 = (__half2*)(dst + (size_t)rel * NN * HH + (size_t)node * HH + cg * 4);
            float2 lo = {acc0.x, acc0.y}, hi = {acc0.z, acc0.w};
            H2[0] = __float22half2_rn(lo);
            H2[1] = __float22half2_rn(hi);
        }
        {
            __half2* H2 = (__half2*)(dst + (size_t)rel * NN * HH + (size_t)(node + 1) * HH + cg * 4);
            float2 lo = {acc1.x, acc1.y}, hi = {acc1.z, acc1.w};
            H2[0] = __float22half2_rn(lo);
            H2[1] = __float22half2_rn(hi);
        }
        __syncthreads();                        // Ws reads done before next staging
    }
}

// ---------------- fused: input GEMM + layer-0 K/Q/V ----------------
__global__ __launch_bounds__(256) void in_kqv(
        const float* __restrict__ xn1, const float* __restrict__ xn2,
        const float* __restrict__ Win, const float* __restrict__ b_in,
        const float* __restrict__ Wk, const float* __restrict__ Wq,
        const float* __restrict__ Wv,
        const float* __restrict__ bk, const float* __restrict__ bq,
        const float* __restrict__ bv,
        __half* Kh, __half* Qh, __half* Vh) {
    int z = blockIdx.z;
    int tid = threadIdx.x;
    int row0 = blockIdx.x * 16;
    __shared__ float As[16 * DIN];              // 8 KB
    __shared__ float Ws[DIN * HD];              // 32 KB
    __shared__ float Xs[16 * HD];               // 4 KB
    float4* As4 = (float4*)As;
    float4* Ws4 = (float4*)Ws;
    float4* Xs4 = (float4*)Xs;
    {
        const float4* A4 = (const float4*)(z ? xn2 : xn1);
        const float4* W4 = (const float4*)(Win + (size_t)z * DIN * HD);
        const float4* b4 = (const float4*)(b_in + (size_t)z * HD);
        As4[tid]       = A4[(size_t)row0 * 32 + tid];
        As4[tid + 256] = A4[(size_t)row0 * 32 + tid + 256];
        #pragma unroll
        for (int i = 0; i < 8; i++) Ws4[tid + 256 * i] = W4[tid + 256 * i];
        __syncthreads();
        int r = tid >> 4, cg = tid & 15;
        float4 acc = b4[cg];
        const float* a = &As[r * DIN];
        for (int k = 0; k < DIN; k++) {
            float av = a[k];
            float4 w = Ws4[k * 16 + cg];
            acc.x += av * w.x; acc.y += av * w.y; acc.z += av * w.z; acc.w += av * w.w;
        }
        acc.x = fmaxf(acc.x, 0.f); acc.y = fmaxf(acc.y, 0.f);
        acc.z = fmaxf(acc.z, 0.f); acc.w = fmaxf(acc.w, 0.f);
        Xs4[r * 16 + cg] = acc;
        __syncthreads();
    }
    kqv_phases(z, 0, Xs, Ws4, row0, tid, Wk, Wq, Wv, bk, bq, bv, Kh, Qh, Vh);
}

// ---------------- fused: out GEMM (layer l) + K/Q/V (layer l+1) ----------------
__global__ __launch_bounds__(256) void out_kqv(
        const float* __restrict__ aggb,
        const float* __restrict__ Wout, const float* __restrict__ bout,
        const float* __restrict__ sums, int l,
        const float* __restrict__ Wk, const float* __restrict__ Wq,
        const float* __restrict__ Wv,
        const float* __restrict__ bk, const float* __restrict__ bq,
        const float* __restrict__ bv,
        __half* Kh, __half* Qh, __half* Vh,
        __half2* Emh2, __half2* Edh2) {
    int z = blockIdx.z;
    int sel = z ? 0 : 1;                        // which relation's aggregate
    int tid = threadIdx.x;
    int row0 = blockIdx.x * 16;
    __shared__ float As[16 * HH];               // 8 KB
    __shared__ float Ws[HH * HD];               // 32 KB
    __shared__ float Xs[16 * HD];               // 4 KB
    __shared__ float invs[2];
    float4* As4 = (float4*)As;
    float4* Ws4 = (float4*)Ws;
    float4* Xs4 = (float4*)Xs;
    {
        const float4* A4 = (const float4*)(aggb + (size_t)sel * NN * HH);
        const float4* W4 = (const float4*)(Wout + (size_t)(l * 2 + z) * HH * HD);
        const float4* b4 = (const float4*)(bout + (size_t)(l * 2 + z) * HD);
        __half2* E2 = z ? Edh2 : Emh2;
        if (tid < 128) {
            int h = tid >> 6;
            float v = sums[l * 256 + sel * 128 + h * 64 + (tid & 63)];
            #pragma unroll
            for (int off = 1; off <= 32; off <<= 1) v += __shfl_xor(v, off);
            if ((tid & 63) == 0) invs[h] = 1.f / v;
        }
        __syncthreads();
        float inv0 = invs[0], inv1 = invs[1];
        {
            float4 t0 = A4[(size_t)row0 * 32 + tid];
            float4 t1 = A4[(size_t)row0 * 32 + tid + 256];
            float s0 = ((tid & 31) < 16) ? inv0 : inv1;   // cols 0-63 = head0
            t0.x *= s0; t0.y *= s0; t0.z *= s0; t0.w *= s0;
            t1.x *= s0; t1.y *= s0; t1.z *= s0; t1.w *= s0;
            As4[tid] = t0; As4[tid + 256] = t1;
        }
        #pragma unroll
        for (int i = 0; i < 8; i++) Ws4[tid + 256 * i] = W4[tid + 256 * i];
        __syncthreads();
        int r = tid >> 4, cg = tid & 15;
        float4 acc = b4[cg];
        const float* a = &As[r * HH];
        for (int k = 0; k < HH; k++) {
            float av = a[k];
            float4 w = Ws4[k * 16 + cg];
            acc.x += av * w.x; acc.y += av * w.y; acc.z += av * w.z; acc.w += av * w.w;
        }
        int node = row0 + r;
        Xs4[r * 16 + cg] = acc;
        float2 lo = {acc.x, acc.y}, hi = {acc.z, acc.w};
        E2[(size_t)node * 64 + l * 32 + cg * 2]     = __float22half2_rn(lo);
        E2[(size_t)node * 64 + l * 32 + cg * 2 + 1] = __float22half2_rn(hi);
        __syncthreads();
    }
    kqv_phases(z, l + 1, Xs, Ws4, row0, tid, Wk, Wq, Wv, bk, bq, bv, Kh, Qh, Vh);
}

// ---------------- final out GEMM (layer 1; Em/Ed only) ----------------
__global__ __launch_bounds__(256) void out_last(
        const float* __restrict__ aggb,
        const float* __restrict__ Wout, const float* __restrict__ bout,
        const float* __restrict__ sums, int l,
        __half2* Emh2, __half2* Edh2) {
    int z = blockIdx.z;
    int sel = z ? 0 : 1;
    const float4* A4 = (const float4*)(aggb + (size_t)sel * NN * HH);
    const float4* W4 = (const float4*)(Wout + (size_t)(l * 2 + z) * HH * HD);
    const float4* b4 = (const float4*)(bout + (size_t)(l * 2 + z) * HD);
    __half2* E2 = z ? Edh2 : Emh2;
    __shared__ float As[16 * HH];
    __shared__ float Ws[HH * HD];
    __shared__ float invs[2];
    int tid = threadIdx.x;
    if (tid < 128) {
        int h = tid >> 6;
        float v = sums[l * 256 + sel * 128 + h * 64 + (tid & 63)];
        #pragma unroll
        for (int off = 1; off <= 32; off <<= 1) v += __shfl_xor(v, off);
        if ((tid & 63) == 0) invs[h] = 1.f / v;
    }
    __syncthreads();
    float inv0 = invs[0], inv1 = invs[1];
    int row0 = blockIdx.x * 16;
    float4* As4 = (float4*)As;
    float4* Ws4 = (float4*)Ws;
    {
        float4 t0 = A4[(size_t)row0 * 32 + tid];
        float4 t1 = A4[(size_t)row0 * 32 + tid + 256];
        float s0 = ((tid & 31) < 16) ? inv0 : inv1;
        t0.x *= s0; t0.y *= s0; t0.z *= s0; t0.w *= s0;
        t1.x *= s0; t1.y *= s0; t1.z *= s0; t1.w *= s0;
        As4[tid] = t0; As4[tid + 256] = t1;
    }
    #pragma unroll
    for (int i = 0; i < 8; i++) Ws4[tid + 256 * i] = W4[tid + 256 * i];
    __syncthreads();
    int r = tid >> 4, cg = tid & 15;
    float4 acc = b4[cg];
    const float* a = &As[r * HH];
    for (int k = 0; k < HH; k++) {
        float av = a[k];
        float4 w = Ws4[k * 16 + cg];
        acc.x += av * w.x; acc.y += av * w.y; acc.z += av * w.z; acc.w += av * w.w;
    }
    int node = row0 + r;
    float2 lo = {acc.x, acc.y}, hi = {acc.z, acc.w};
    E2[(size_t)node * 64 + l * 32 + cg * 2]     = __float22half2_rn(lo);
    E2[(size_t)node * 64 + l * 32 + cg * 2 + 1] = __float22half2_rn(hi);
}

// ---------------- single-pass fused attention: block = (rel, 8 dest nodes) ----
// 16-LANE GROUP PER EDGE: lane s owns chunk s of K/Q/V (3 loads/edge); dot
// reduces in 3 shfl steps within each 8-lane half, so lanes 0-7 hold head0's
// logit and 8-15 head1's -- matching their V chunk's head. acc = 8 regs/lane.
// Wave owns 2 nodes (4 groups); cross-group reduce = 2 shfl steps x 8 regs.
__global__ __launch_bounds__(256) void conv_fused(
        const int* __restrict__ ptr12, const int2* __restrict__ rc12,
        const int* __restrict__ ptr21, const int2* __restrict__ rc21,
        const __half* __restrict__ Kh, const __half* __restrict__ Qh,
        const __half* __restrict__ Vh,
        float* __restrict__ aggb, float* __restrict__ sums, int l) {
    int b = blockIdx.x;
    int rel = b & 1, seg = b >> 1;              // seg in [0, 1250)
    const int* __restrict__ ptr = rel ? ptr21 : ptr12;
    const int2* __restrict__ rc = rel ? rc21 : rc12;
    const uint4* K = (const uint4*)(Kh + (size_t)rel * NN * HH);
    const uint4* Q = (const uint4*)(Qh + (size_t)rel * NN * HH);
    const uint4* V = (const uint4*)(Vh + (size_t)rel * NN * HH);
    float4* A4 = (float4*)(aggb + (size_t)rel * NN * HH);
    int tid = threadIdx.x;
    int wave = tid >> 6, lane = tid & 63;
    int g = lane >> 4, s = lane & 15;           // group 0..3, chunk 0..15
    int c0 = seg * 8;
    float sE = 0.f;                             // lane0: head0 partial, lane8: head1
    bool sl0 = (s == 0), sl8 = (s == 8);
    #pragma unroll
    for (int ni = 0; ni < 2; ni++) {
        int c = c0 + wave * 2 + ni;
        int jb = ptr[c], je = ptr[c + 1];
        float acc[8] = {0,0,0,0,0,0,0,0};
        for (int j = jb + g; j < je; j += 4) {
            int2 e = rc[j];
            uint4 k = K[(size_t)e.x * 16 + s];
            uint4 q = Q[(size_t)e.y * 16 + s];
            uint4 v = V[(size_t)e.x * 16 + s];
            float p = dotc(k, q);
            #pragma unroll
            for (int off = 1; off <= 4; off <<= 1)   // reduce within 8-lane half
                p += __shfl_xor(p, off);
            p *= 0.125f;
            p = p > 0.f ? p : 0.2f * p;
            float ee = __expf(p);
            acc8(v, ee, acc);
            if (sl0 | sl8) sE += ee;
        }
        // cross-group reduce (4 groups hold disjoint edge subsets of this node)
        #pragma unroll
        for (int i = 0; i < 8; i++) {
            acc[i] += __shfl_xor(acc[i], 16);
            acc[i] += __shfl_xor(acc[i], 32);
        }
        if (g == 0) {                           // 16 lanes write the full 128-f row
            float4 a0 = {acc[0], acc[1], acc[2], acc[3]};
            float4 a1 = {acc[4], acc[5], acc[6], acc[7]};
            A4[(size_t)c * 32 + 2 * s]     = a0;
            A4[(size_t)c * 32 + 2 * s + 1] = a1;
        }
    }
    // exp-sums: nonzero on lanes s==0 (head0) and s==8 (head1); fold groups
    sE += __shfl_xor(sE, 16);
    sE += __shfl_xor(sE, 32);
    __shared__ float sred[4][2];
    if (lane == 0) sred[wave][0] = sE;
    else if (lane == 8) sred[wave][1] = sE;
    __syncthreads();
    if (tid < 2) {
        float t = sred[0][tid] + sred[1][tid] + sred[2][tid] + sred[3][tid];
        atomicAdd(&sums[l * 256 + rel * 128 + tid * 64 + (seg & 63)], t);
    }
}

// ---------------- prediction (8-lane group per pair, fdot2) ----------------
__global__ __launch_bounds__(256) void pred_kernel(
        const __half* __restrict__ Emh, const __half* __restrict__ Edh,
        const int* __restrict__ pe, float* out) {
    int grp = (blockIdx.x * 256 + threadIdx.x) >> 3;   // pair index
    int s8 = threadIdx.x & 7;
    if (grp >= NP) return;
    int m = pe[grp], d = pe[NP + grp];
    const uint4* a = (const uint4*)Emh + (size_t)m * 16;
    const uint4* b = (const uint4*)Edh + (size_t)d * 16;
    float acc = dotc(a[s8], b[s8]) + dotc(a[8 + s8], b[8 + s8]);
    #pragma unroll
    for (int off = 1; off <= 4; off <<= 1) acc += __shfl_xor(acc, off);
    if (s8 == 0) out[grp] = acc;
}

// ---------------- host ----------------

extern "C" void kernel_launch(void* const* d_in, const int* in_sizes, int n_in,
                              void* d_out, int out_size, void* d_ws, size_t ws_size,
                              hipStream_t stream) {
    (void)in_sizes; (void)n_in; (void)out_size; (void)ws_size;
    const float* x_n1 = (const float*)d_in[0];
    const float* x_n2 = (const float*)d_in[1];
    const int*   e12  = (const int*)d_in[2];
    const int*   e21  = (const int*)d_in[3];
    const int*   pe   = (const int*)d_in[4];
    const float* Win  = (const float*)d_in[5];
    const float* b_in = (const float*)d_in[6];
    const float* Wk   = (const float*)d_in[7];
    const float* bk   = (const float*)d_in[8];
    const float* Wq   = (const float*)d_in[9];
    const float* bq   = (const float*)d_in[10];
    const float* Wv   = (const float*)d_in[11];
    const float* bv   = (const float*)d_in[12];
    const float* Wout = (const float*)d_in[13];
    const float* bout = (const float*)d_in[14];
    float* out = (float*)d_out;

    char* w = (char*)d_ws;
    auto carve = [&](size_t nbytes) -> void* {
        void* p = (void*)w;
        w += (nbytes + 255) & ~(size_t)255;
        return p;
    };
    __half* Kh   = (__half*)carve((size_t)2 * NN * HH * 2);
    __half* Qh   = (__half*)carve((size_t)2 * NN * HH * 2);
    __half* Vh   = (__half*)carve((size_t)2 * NN * HH * 2);
    float* aggb  = (float*)carve((size_t)2 * NN * HH * 4);
    __half2* Emh2 = (__half2*)carve((size_t)NN * HH * 2);
    __half2* Edh2 = (__half2*)carve((size_t)NN * HH * 2);
    int* cnt     = (int*)carve((size_t)2 * NN * 4);    // cnt + sums: one memset
    float* sums  = (float*)carve((size_t)2 * 256 * 4);
    int* cur12   = (int*)carve((size_t)NN * 4);
    int* cur21   = (int*)carve((size_t)NN * 4);
    int* ptr12   = (int*)carve((size_t)(NN + 1) * 4);
    int* ptr21   = (int*)carve((size_t)(NN + 1) * 4);
    int2* rc12   = (int2*)carve((size_t)NE * 8);
    int2* rc21   = (int2*)carve((size_t)NE * 8);
    int* cnt12 = cnt;
    int* cnt21 = cnt + NN;

    // zero cnt + sums (adjacent carves) in one memset
    size_t zbytes = (((size_t)2 * NN * 4 + 255) & ~(size_t)255) + (size_t)2 * 256 * 4;
    hipMemsetAsync(cnt, 0, zbytes, stream);

    // CSR build
    int eb = (2 * NE + 255) / 256;
    count_kernel<<<(NE / 2 + 255) / 256, 256, 0, stream>>>(e12, e21, cnt12, cnt21);
    scan_kernel<<<2, 1024, 0, stream>>>(cnt12, cnt21, ptr12, ptr21, cur12, cur21);
    fill_kernel<<<eb, 256, 0, stream>>>(e12, e21, cur12, cur21, rc12, rc21);

    // input linear + relu fused with layer-0 K/Q/V (x lives only in LDS)
    in_kqv<<<dim3(NN / 16, 1, 2), 256, 0, stream>>>(
        x_n1, x_n2, Win, b_in, Wk, Wq, Wv, bk, bq, bv, Kh, Qh, Vh);

    conv_fused<<<dim3(NN / 8 * 2), 256, 0, stream>>>(
        ptr12, rc12, ptr21, rc21, Kh, Qh, Vh, aggb, sums, 0);

    // out GEMM layer 0 fused with layer-1 K/Q/V
    out_kqv<<<dim3(NN / 16, 1, 2), 256, 0, stream>>>(
        aggb, Wout, bout, sums, 0, Wk, Wq, Wv, bk, bq, bv, Kh, Qh, Vh, Emh2, Edh2);

    conv_fused<<<dim3(NN / 8 * 2), 256, 0, stream>>>(
        ptr12, rc12, ptr21, rc21, Kh, Qh, Vh, aggb, sums, 1);

    out_last<<<dim3(NN / 16, 1, 2), 256, 0, stream>>>(
        aggb, Wout, bout, sums, 1, Emh2, Edh2);

    pred_kernel<<<(NP * 8 + 255) / 256, 256, 0, stream>>>(
        (const __half*)Emh2, (const __half*)Edh2, pe, out);
}

// Round 18
// 218.840 us; speedup vs baseline: 1.0394x; 1.0394x over previous
//
#include <hip/hip_runtime.h>
#include <hip/hip_fp16.h>

#define NN 10000
#define DIN 128
#define HD 64
#define HH 128          // H*HEADS
#define NE 250000
#define NP 100000

typedef _Float16 h2v __attribute__((ext_vector_type(2)));

// ---------------- CSR build ----------------

// int4-vectorized: 4 cols per thread
__global__ void count_kernel(const int* e12, const int* e21, int* cnt12, int* cnt21) {
    int t = blockIdx.x * blockDim.x + threadIdx.x;
    if (t < NE / 4) {
        int4 c = ((const int4*)(e12 + NE))[t];
        atomicAdd(&cnt12[c.x], 1); atomicAdd(&cnt12[c.y], 1);
        atomicAdd(&cnt12[c.z], 1); atomicAdd(&cnt12[c.w], 1);
    } else if (t < NE / 2) {
        int4 c = ((const int4*)(e21 + NE))[t - NE / 4];
        atomicAdd(&cnt21[c.x], 1); atomicAdd(&cnt21[c.y], 1);
        atomicAdd(&cnt21[c.z], 1); atomicAdd(&cnt21[c.w], 1);
    }
}

__global__ void scan_kernel(const int* cnt12, const int* cnt21,
                            int* ptr12, int* ptr21, int* cur12, int* cur21) {
    const int* cnt = blockIdx.x ? cnt21 : cnt12;
    int* ptr = blockIdx.x ? ptr21 : ptr12;
    int* cur = blockIdx.x ? cur21 : cur12;
    const int T = 1024, C = 10;                 // 1024*10 = 10240 >= 10000
    __shared__ int sm[1024];
    int t = threadIdx.x;
    int v[C]; int tot = 0;
    int base = t * C;
    #pragma unroll
    for (int i = 0; i < C; i++) {
        int id = base + i;
        v[i] = (id < NN) ? cnt[id] : 0;
        tot += v[i];
    }
    sm[t] = tot; __syncthreads();
    for (int off = 1; off < T; off <<= 1) {
        int x = (t >= off) ? sm[t - off] : 0;
        __syncthreads();
        sm[t] += x;
        __syncthreads();
    }
    int run = sm[t] - tot;                      // exclusive prefix
    #pragma unroll
    for (int i = 0; i < C; i++) {
        int id = base + i;
        if (id < NN) { ptr[id] = run; cur[id] = run; }
        run += v[i];
    }
    if (t == T - 1) ptr[NN] = run;
}

// writes packed (row, col) per CSR slot
__global__ void fill_kernel(const int* e12, const int* e21,
                            int* cur12, int* cur21, int2* rc12, int2* rc21) {
    int t = blockIdx.x * blockDim.x + threadIdx.x;
    if (t < NE) {
        int c = e12[NE + t];
        int p = atomicAdd(&cur12[c], 1);
        rc12[p] = make_int2(e12[t], c);
    } else if (t < 2 * NE) {
        int e = t - NE;
        int c = e21[NE + e];
        int p = atomicAdd(&cur21[c], 1);
        rc21[p] = make_int2(e21[e], c);
    }
}

// ---------------- shared device pieces ----------------

__device__ __forceinline__ float dotc(const uint4& k, const uint4& q) {
#if __has_builtin(__builtin_amdgcn_fdot2)
    const h2v* kh = (const h2v*)&k;
    const h2v* qh = (const h2v*)&q;
    float s = 0.f;
    #pragma unroll
    for (int i = 0; i < 4; i++)
        s = __builtin_amdgcn_fdot2(kh[i], qh[i], s, false);
    return s;
#else
    const __half2* kh = (const __half2*)&k;
    const __half2* qh = (const __half2*)&q;
    float s = 0.f;
    #pragma unroll
    for (int i = 0; i < 4; i++) {
        float2 a = __half22float2(kh[i]);
        float2 b = __half22float2(qh[i]);
        s += a.x * b.x + a.y * b.y;
    }
    return s;
#endif
}
__device__ __forceinline__ void acc8(const uint4& v, float e, float* acc) {
    const __half2* h = (const __half2*)&v;
    float2 f0 = __half22float2(h[0]), f1 = __half22float2(h[1]);
    float2 f2 = __half22float2(h[2]), f3 = __half22float2(h[3]);
    acc[0] += e*f0.x; acc[1] += e*f0.y; acc[2] += e*f1.x; acc[3] += e*f1.y;
    acc[4] += e*f2.x; acc[5] += e*f2.y; acc[6] += e*f3.x; acc[7] += e*f3.y;
}

// 3 K/Q/V GEMM phases over the block's 16 x-rows held in LDS (Xs, 16x64 f32).
// node type z: K,V -> rel=z ; Q -> rel=1-z. W staged in Ws (32 KB) per phase.
__device__ __forceinline__ void kqv_phases(
        int z, int l, const float* Xs, float4* Ws4, int row0, int tid,
        const float* __restrict__ Wk, const float* __restrict__ Wq,
        const float* __restrict__ Wv,
        const float* __restrict__ bk, const float* __restrict__ bq,
        const float* __restrict__ bv,
        __half* Kh, __half* Qh, __half* Vh) {
    #pragma unroll
    for (int kind = 0; kind < 3; kind++) {
        int rel = (kind == 1) ? (1 - z) : z;
        size_t wo = (size_t)(l * 2 + rel) * HD * HH;
        size_t bo = (size_t)(l * 2 + rel) * HH;
        const float4* W4 = (const float4*)((kind == 0 ? Wk : kind == 1 ? Wq : Wv) + wo);
        const float4* b4 = (const float4*)((kind == 0 ? bk : kind == 1 ? bq : bv) + bo);
        #pragma unroll
        for (int i = 0; i < 8; i++) Ws4[tid + 256 * i] = W4[tid + 256 * i];
        __syncthreads();
        int cg = tid & 31, rg = tid >> 5;       // rg 0..7, rows rg*2, rg*2+1
        float4 acc0 = b4[cg], acc1 = acc0;
        const float* a0 = &Xs[(rg * 2) * HD];
        const float* a1 = &Xs[(rg * 2 + 1) * HD];
        for (int k = 0; k < HD; k++) {
            float4 w = Ws4[k * 32 + cg];
            float v0 = a0[k], v1 = a1[k];
            acc0.x += v0 * w.x; acc0.y += v0 * w.y; acc0.z += v0 * w.z; acc0.w += v0 * w.w;
            acc1.x += v1 * w.x; acc1.y += v1 * w.y; acc1.z += v1 * w.z; acc1.w += v1 * w.w;
        }
        __half* dst = (kind == 0) ? Kh : (kind == 1) ? Qh : Vh;
        int node = row0 + rg * 2;
        {
            __half2* H2 = (__half2*)(dst + (size_t)rel * NN * HH + (size_t)node * HH + cg * 4);
            float2 lo = {acc0.x, acc0.y}, hi = {acc0.z, acc0.w};
            H2[0] = __float22half2_rn(lo);
            H2[1] = __float22half2_rn(hi);
        }
        {
            __half2* H2 = (__half2*)(dst + (size_t)rel * NN * HH + (size_t)(node + 1) * HH + cg * 4);
            float2 lo = {acc1.x, acc1.y}, hi = {acc1.z, acc1.w};
            H2[0] = __float22half2_rn(lo);
            H2[1] = __float22half2_rn(hi);
        }
        __syncthreads();                        // Ws reads done before next staging
    }
}

// ---------------- fused: input GEMM + layer-0 K/Q/V ----------------
__global__ __launch_bounds__(256) void in_kqv(
        const float* __restrict__ xn1, const float* __restrict__ xn2,
        const float* __restrict__ Win, const float* __restrict__ b_in,
        const float* __restrict__ Wk, const float* __restrict__ Wq,
        const float* __restrict__ Wv,
        const float* __restrict__ bk, const float* __restrict__ bq,
        const float* __restrict__ bv,
        __half* Kh, __half* Qh, __half* Vh) {
    int z = blockIdx.z;
    int tid = threadIdx.x;
    int row0 = blockIdx.x * 16;
    __shared__ float As[16 * DIN];              // 8 KB
    __shared__ float Ws[DIN * HD];              // 32 KB
    __shared__ float Xs[16 * HD];               // 4 KB
    float4* As4 = (float4*)As;
    float4* Ws4 = (float4*)Ws;
    float4* Xs4 = (float4*)Xs;
    {
        const float4* A4 = (const float4*)(z ? xn2 : xn1);
        const float4* W4 = (const float4*)(Win + (size_t)z * DIN * HD);
        const float4* b4 = (const float4*)(b_in + (size_t)z * HD);
        As4[tid]       = A4[(size_t)row0 * 32 + tid];
        As4[tid + 256] = A4[(size_t)row0 * 32 + tid + 256];
        #pragma unroll
        for (int i = 0; i < 8; i++) Ws4[tid + 256 * i] = W4[tid + 256 * i];
        __syncthreads();
        int r = tid >> 4, cg = tid & 15;
        float4 acc = b4[cg];
        const float* a = &As[r * DIN];
        for (int k = 0; k < DIN; k++) {
            float av = a[k];
            float4 w = Ws4[k * 16 + cg];
            acc.x += av * w.x; acc.y += av * w.y; acc.z += av * w.z; acc.w += av * w.w;
        }
        acc.x = fmaxf(acc.x, 0.f); acc.y = fmaxf(acc.y, 0.f);
        acc.z = fmaxf(acc.z, 0.f); acc.w = fmaxf(acc.w, 0.f);
        Xs4[r * 16 + cg] = acc;
        __syncthreads();
    }
    kqv_phases(z, 0, Xs, Ws4, row0, tid, Wk, Wq, Wv, bk, bq, bv, Kh, Qh, Vh);
}

// ---------------- fused: out GEMM (layer l) + K/Q/V (layer l+1) ----------------
__global__ __launch_bounds__(256) void out_kqv(
        const float* __restrict__ aggb,
        const float* __restrict__ Wout, const float* __restrict__ bout,
        const float* __restrict__ sums, int l,
        const float* __restrict__ Wk, const float* __restrict__ Wq,
        const float* __restrict__ Wv,
        const float* __restrict__ bk, const float* __restrict__ bq,
        const float* __restrict__ bv,
        __half* Kh, __half* Qh, __half* Vh,
        __half2* Emh2, __half2* Edh2) {
    int z = blockIdx.z;
    int sel = z ? 0 : 1;                        // which relation's aggregate
    int tid = threadIdx.x;
    int row0 = blockIdx.x * 16;
    __shared__ float As[16 * HH];               // 8 KB
    __shared__ float Ws[HH * HD];               // 32 KB
    __shared__ float Xs[16 * HD];               // 4 KB
    __shared__ float invs[2];
    float4* As4 = (float4*)As;
    float4* Ws4 = (float4*)Ws;
    float4* Xs4 = (float4*)Xs;
    {
        const float4* A4 = (const float4*)(aggb + (size_t)sel * NN * HH);
        const float4* W4 = (const float4*)(Wout + (size_t)(l * 2 + z) * HH * HD);
        const float4* b4 = (const float4*)(bout + (size_t)(l * 2 + z) * HD);
        __half2* E2 = z ? Edh2 : Emh2;
        if (tid < 128) {
            int h = tid >> 6;
            float v = sums[l * 256 + sel * 128 + h * 64 + (tid & 63)];
            #pragma unroll
            for (int off = 1; off <= 32; off <<= 1) v += __shfl_xor(v, off);
            if ((tid & 63) == 0) invs[h] = 1.f / v;
        }
        __syncthreads();
        float inv0 = invs[0], inv1 = invs[1];
        {
            float4 t0 = A4[(size_t)row0 * 32 + tid];
            float4 t1 = A4[(size_t)row0 * 32 + tid + 256];
            float s0 = ((tid & 31) < 16) ? inv0 : inv1;   // cols 0-63 = head0
            t0.x *= s0; t0.y *= s0; t0.z *= s0; t0.w *= s0;
            t1.x *= s0; t1.y *= s0; t1.z *= s0; t1.w *= s0;
            As4[tid] = t0; As4[tid + 256] = t1;
        }
        #pragma unroll
        for (int i = 0; i < 8; i++) Ws4[tid + 256 * i] = W4[tid + 256 * i];
        __syncthreads();
        int r = tid >> 4, cg = tid & 15;
        float4 acc = b4[cg];
        const float* a = &As[r * HH];
        for (int k = 0; k < HH; k++) {
            float av = a[k];
            float4 w = Ws4[k * 16 + cg];
            acc.x += av * w.x; acc.y += av * w.y; acc.z += av * w.z; acc.w += av * w.w;
        }
        int node = row0 + r;
        Xs4[r * 16 + cg] = acc;
        float2 lo = {acc.x, acc.y}, hi = {acc.z, acc.w};
        E2[(size_t)node * 64 + l * 32 + cg * 2]     = __float22half2_rn(lo);
        E2[(size_t)node * 64 + l * 32 + cg * 2 + 1] = __float22half2_rn(hi);
        __syncthreads();
    }
    kqv_phases(z, l + 1, Xs, Ws4, row0, tid, Wk, Wq, Wv, bk, bq, bv, Kh, Qh, Vh);
}

// ---------------- final out GEMM (layer 1; Em/Ed only) ----------------
__global__ __launch_bounds__(256) void out_last(
        const float* __restrict__ aggb,
        const float* __restrict__ Wout, const float* __restrict__ bout,
        const float* __restrict__ sums, int l,
        __half2* Emh2, __half2* Edh2) {
    int z = blockIdx.z;
    int sel = z ? 0 : 1;
    const float4* A4 = (const float4*)(aggb + (size_t)sel * NN * HH);
    const float4* W4 = (const float4*)(Wout + (size_t)(l * 2 + z) * HH * HD);
    const float4* b4 = (const float4*)(bout + (size_t)(l * 2 + z) * HD);
    __half2* E2 = z ? Edh2 : Emh2;
    __shared__ float As[16 * HH];
    __shared__ float Ws[HH * HD];
    __shared__ float invs[2];
    int tid = threadIdx.x;
    if (tid < 128) {
        int h = tid >> 6;
        float v = sums[l * 256 + sel * 128 + h * 64 + (tid & 63)];
        #pragma unroll
        for (int off = 1; off <= 32; off <<= 1) v += __shfl_xor(v, off);
        if ((tid & 63) == 0) invs[h] = 1.f / v;
    }
    __syncthreads();
    float inv0 = invs[0], inv1 = invs[1];
    int row0 = blockIdx.x * 16;
    float4* As4 = (float4*)As;
    float4* Ws4 = (float4*)Ws;
    {
        float4 t0 = A4[(size_t)row0 * 32 + tid];
        float4 t1 = A4[(size_t)row0 * 32 + tid + 256];
        float s0 = ((tid & 31) < 16) ? inv0 : inv1;
        t0.x *= s0; t0.y *= s0; t0.z *= s0; t0.w *= s0;
        t1.x *= s0; t1.y *= s0; t1.z *= s0; t1.w *= s0;
        As4[tid] = t0; As4[tid + 256] = t1;
    }
    #pragma unroll
    for (int i = 0; i < 8; i++) Ws4[tid + 256 * i] = W4[tid + 256 * i];
    __syncthreads();
    int r = tid >> 4, cg = tid & 15;
    float4 acc = b4[cg];
    const float* a = &As[r * HH];
    for (int k = 0; k < HH; k++) {
        float av = a[k];
        float4 w = Ws4[k * 16 + cg];
        acc.x += av * w.x; acc.y += av * w.y; acc.z += av * w.z; acc.w += av * w.w;
    }
    int node = row0 + r;
    float2 lo = {acc.x, acc.y}, hi = {acc.z, acc.w};
    E2[(size_t)node * 64 + l * 32 + cg * 2]     = __float22half2_rn(lo);
    E2[(size_t)node * 64 + l * 32 + cg * 2 + 1] = __float22half2_rn(hi);
}

// ---------------- single-pass fused attention: block = (rel, 8 dest nodes) ----
// 8-lane group per edge, 2 edges per iteration (12 loads in flight per lane).
// Wave owns 2 nodes; cross-group reduce = 3 shfl steps; lanes g==0 write row.
__global__ __launch_bounds__(256) void conv_fused(
        const int* __restrict__ ptr12, const int2* __restrict__ rc12,
        const int* __restrict__ ptr21, const int2* __restrict__ rc21,
        const __half* __restrict__ Kh, const __half* __restrict__ Qh,
        const __half* __restrict__ Vh,
        float* __restrict__ aggb, float* __restrict__ sums, int l) {
    int b = blockIdx.x;
    int rel = b & 1, seg = b >> 1;              // seg in [0, 1250)
    const int* __restrict__ ptr = rel ? ptr21 : ptr12;
    const int2* __restrict__ rc = rel ? rc21 : rc12;
    const uint4* K = (const uint4*)(Kh + (size_t)rel * NN * HH);
    const uint4* Q = (const uint4*)(Qh + (size_t)rel * NN * HH);
    const uint4* V = (const uint4*)(Vh + (size_t)rel * NN * HH);
    float4* A4 = (float4*)(aggb + (size_t)rel * NN * HH);
    int tid = threadIdx.x;
    int wave = tid >> 6, lane = tid & 63;
    int g = lane >> 3, s8 = lane & 7;           // group 0..7, lane-in-group
    int c0 = seg * 8;
    float s0 = 0.f, s1 = 0.f;
    #pragma unroll
    for (int ni = 0; ni < 2; ni++) {
        int c = c0 + wave * 2 + ni;
        int jb = ptr[c], je = ptr[c + 1];
        float accA[8] = {0,0,0,0,0,0,0,0};
        float accB[8] = {0,0,0,0,0,0,0,0};
        for (int j = jb + g; j < je; j += 16) {
            int2 eA = rc[j];
            int jB = j + 8;
            bool hB = jB < je;
            int2 eB = hB ? rc[jB] : make_int2(0, 0);
            const uint4* kpA = K + (size_t)eA.x * 16;
            const uint4* qpA = Q + (size_t)eA.y * 16;
            const uint4* vpA = V + (size_t)eA.x * 16;
            const uint4* kpB = K + (size_t)eB.x * 16;
            const uint4* qpB = Q + (size_t)eB.y * 16;
            const uint4* vpB = V + (size_t)eB.x * 16;
            uint4 kA0 = kpA[s8],     qA0 = qpA[s8],     vA0 = vpA[s8];
            uint4 kA1 = kpA[8 + s8], qA1 = qpA[8 + s8], vA1 = vpA[8 + s8];
            uint4 kB0 = kpB[s8],     qB0 = qpB[s8],     vB0 = vpB[s8];
            uint4 kB1 = kpB[8 + s8], qB1 = qpB[8 + s8], vB1 = vpB[8 + s8];
            float pA0 = dotc(kA0, qA0), pA1 = dotc(kA1, qA1);
            float pB0 = dotc(kB0, qB0), pB1 = dotc(kB1, qB1);
            #pragma unroll
            for (int off = 1; off <= 4; off <<= 1) {   // butterfly within 8 lanes
                pA0 += __shfl_xor(pA0, off);
                pA1 += __shfl_xor(pA1, off);
                pB0 += __shfl_xor(pB0, off);
                pB1 += __shfl_xor(pB1, off);
            }
            pA0 *= 0.125f; pA1 *= 0.125f; pB0 *= 0.125f; pB1 *= 0.125f;
            pA0 = pA0 > 0.f ? pA0 : 0.2f * pA0;
            pA1 = pA1 > 0.f ? pA1 : 0.2f * pA1;
            pB0 = pB0 > 0.f ? pB0 : 0.2f * pB0;
            pB1 = pB1 > 0.f ? pB1 : 0.2f * pB1;
            float eA0 = __expf(pA0), eA1 = __expf(pA1);
            float eB0 = hB ? __expf(pB0) : 0.f;
            float eB1 = hB ? __expf(pB1) : 0.f;
            acc8(vA0, eA0, accA);
            acc8(vA1, eA1, accB);
            acc8(vB0, eB0, accA);
            acc8(vB1, eB1, accB);
            if (s8 == 0) { s0 += eA0; s0 += eB0; s1 += eA1; s1 += eB1; }
        }
        // cross-group reduce (groups hold disjoint edge subsets of this node)
        #pragma unroll
        for (int i = 0; i < 8; i++) {
            accA[i] += __shfl_xor(accA[i], 8);
            accA[i] += __shfl_xor(accA[i], 16);
            accA[i] += __shfl_xor(accA[i], 32);
            accB[i] += __shfl_xor(accB[i], 8);
            accB[i] += __shfl_xor(accB[i], 16);
            accB[i] += __shfl_xor(accB[i], 32);
        }
        if (g == 0) {                           // lanes 0..7 write the full row
            float4 a0 = {accA[0], accA[1], accA[2], accA[3]};
            float4 a1 = {accA[4], accA[5], accA[6], accA[7]};
            float4 b0 = {accB[0], accB[1], accB[2], accB[3]};
            float4 b1 = {accB[4], accB[5], accB[6], accB[7]};
            A4[(size_t)c * 32 + 2 * s8]          = a0;
            A4[(size_t)c * 32 + 2 * s8 + 1]      = a1;
            A4[(size_t)c * 32 + 16 + 2 * s8]     = b0;
            A4[(size_t)c * 32 + 16 + 2 * s8 + 1] = b1;
        }
    }
    // exp-sum: only s8==0 lanes nonzero -> butterfly over group bits
    s0 += __shfl_xor(s0, 8);  s0 += __shfl_xor(s0, 16); s0 += __shfl_xor(s0, 32);
    s1 += __shfl_xor(s1, 8);  s1 += __shfl_xor(s1, 16); s1 += __shfl_xor(s1, 32);
    __shared__ float sred[4][2];
    if (lane == 0) { sred[wave][0] = s0; sred[wave][1] = s1; }
    __syncthreads();
    if (tid < 2) {
        float t = sred[0][tid] + sred[1][tid] + sred[2][tid] + sred[3][tid];
        atomicAdd(&sums[l * 256 + rel * 128 + tid * 64 + (seg & 63)], t);
    }
}

// ---------------- prediction (8-lane group per pair, fdot2) ----------------
__global__ __launch_bounds__(256) void pred_kernel(
        const __half* __restrict__ Emh, const __half* __restrict__ Edh,
        const int* __restrict__ pe, float* out) {
    int grp = (blockIdx.x * 256 + threadIdx.x) >> 3;   // pair index
    int s8 = threadIdx.x & 7;
    if (grp >= NP) return;
    int m = pe[grp], d = pe[NP + grp];
    const uint4* a = (const uint4*)Emh + (size_t)m * 16;
    const uint4* b = (const uint4*)Edh + (size_t)d * 16;
    float acc = dotc(a[s8], b[s8]) + dotc(a[8 + s8], b[8 + s8]);
    #pragma unroll
    for (int off = 1; off <= 4; off <<= 1) acc += __shfl_xor(acc, off);
    if (s8 == 0) out[grp] = acc;
}

// ---------------- host ----------------

extern "C" void kernel_launch(void* const* d_in, const int* in_sizes, int n_in,
                              void* d_out, int out_size, void* d_ws, size_t ws_size,
                              hipStream_t stream) {
    (void)in_sizes; (void)n_in; (void)out_size; (void)ws_size;
    const float* x_n1 = (const float*)d_in[0];
    const float* x_n2 = (const float*)d_in[1];
    const int*   e12  = (const int*)d_in[2];
    const int*   e21  = (const int*)d_in[3];
    const int*   pe   = (const int*)d_in[4];
    const float* Win  = (const float*)d_in[5];
    const float* b_in = (const float*)d_in[6];
    const float* Wk   = (const float*)d_in[7];
    const float* bk   = (const float*)d_in[8];
    const float* Wq   = (const float*)d_in[9];
    const float* bq   = (const float*)d_in[10];
    const float* Wv   = (const float*)d_in[11];
    const float* bv   = (const float*)d_in[12];
    const float* Wout = (const float*)d_in[13];
    const float* bout = (const float*)d_in[14];
    float* out = (float*)d_out;

    char* w = (char*)d_ws;
    auto carve = [&](size_t nbytes) -> void* {
        void* p = (void*)w;
        w += (nbytes + 255) & ~(size_t)255;
        return p;
    };
    __half* Kh   = (__half*)carve((size_t)2 * NN * HH * 2);
    __half* Qh   = (__half*)carve((size_t)2 * NN * HH * 2);
    __half* Vh   = (__half*)carve((size_t)2 * NN * HH * 2);
    float* aggb  = (float*)carve((size_t)2 * NN * HH * 4);
    __half2* Emh2 = (__half2*)carve((size_t)NN * HH * 2);
    __half2* Edh2 = (__half2*)carve((size_t)NN * HH * 2);
    int* cnt     = (int*)carve((size_t)2 * NN * 4);    // cnt + sums: one memset
    float* sums  = (float*)carve((size_t)2 * 256 * 4);
    int* cur12   = (int*)carve((size_t)NN * 4);
    int* cur21   = (int*)carve((size_t)NN * 4);
    int* ptr12   = (int*)carve((size_t)(NN + 1) * 4);
    int* ptr21   = (int*)carve((size_t)(NN + 1) * 4);
    int2* rc12   = (int2*)carve((size_t)NE * 8);
    int2* rc21   = (int2*)carve((size_t)NE * 8);
    int* cnt12 = cnt;
    int* cnt21 = cnt + NN;

    // zero cnt + sums (adjacent carves) in one memset
    size_t zbytes = (((size_t)2 * NN * 4 + 255) & ~(size_t)255) + (size_t)2 * 256 * 4;
    hipMemsetAsync(cnt, 0, zbytes, stream);

    // CSR build
    int eb = (2 * NE + 255) / 256;
    count_kernel<<<(NE / 2 + 255) / 256, 256, 0, stream>>>(e12, e21, cnt12, cnt21);
    scan_kernel<<<2, 1024, 0, stream>>>(cnt12, cnt21, ptr12, ptr21, cur12, cur21);
    fill_kernel<<<eb, 256, 0, stream>>>(e12, e21, cur12, cur21, rc12, rc21);

    // input linear + relu fused with layer-0 K/Q/V (x lives only in LDS)
    in_kqv<<<dim3(NN / 16, 1, 2), 256, 0, stream>>>(
        x_n1, x_n2, Win, b_in, Wk, Wq, Wv, bk, bq, bv, Kh, Qh, Vh);

    conv_fused<<<dim3(NN / 8 * 2), 256, 0, stream>>>(
        ptr12, rc12, ptr21, rc21, Kh, Qh, Vh, aggb, sums, 0);

    // out GEMM layer 0 fused with layer-1 K/Q/V
    out_kqv<<<dim3(NN / 16, 1, 2), 256, 0, stream>>>(
        aggb, Wout, bout, sums, 0, Wk, Wq, Wv, bk, bq, bv, Kh, Qh, Vh, Emh2, Edh2);

    conv_fused<<<dim3(NN / 8 * 2), 256, 0, stream>>>(
        ptr12, rc12, ptr21, rc21, Kh, Qh, Vh, aggb, sums, 1);

    out_last<<<dim3(NN / 16, 1, 2), 256, 0, stream>>>(
        aggb, Wout, bout, sums, 1, Emh2, Edh2);

    pred_kernel<<<(NP * 8 + 255) / 256, 256, 0, stream>>>(
        (const __half*)Emh2, (const __half*)Edh2, pe, out);
}

// Round 19
// 215.876 us; speedup vs baseline: 1.0537x; 1.0137x over previous
//
#include <hip/hip_runtime.h>
#include <hip/hip_fp16.h>

#define NN 10000
#define DIN 128
#define HD 64
#define HH 128          // H*HEADS
#define NE 250000
#define NP 100000

typedef _Float16 h2v __attribute__((ext_vector_type(2)));

// ---------------- CSR build ----------------

// int4-vectorized: 4 cols per thread
__global__ void count_kernel(const int* e12, const int* e21, int* cnt12, int* cnt21) {
    int t = blockIdx.x * blockDim.x + threadIdx.x;
    if (t < NE / 4) {
        int4 c = ((const int4*)(e12 + NE))[t];
        atomicAdd(&cnt12[c.x], 1); atomicAdd(&cnt12[c.y], 1);
        atomicAdd(&cnt12[c.z], 1); atomicAdd(&cnt12[c.w], 1);
    } else if (t < NE / 2) {
        int4 c = ((const int4*)(e21 + NE))[t - NE / 4];
        atomicAdd(&cnt21[c.x], 1); atomicAdd(&cnt21[c.y], 1);
        atomicAdd(&cnt21[c.z], 1); atomicAdd(&cnt21[c.w], 1);
    }
}

__global__ void scan_kernel(const int* cnt12, const int* cnt21,
                            int* ptr12, int* ptr21, int* cur12, int* cur21) {
    const int* cnt = blockIdx.x ? cnt21 : cnt12;
    int* ptr = blockIdx.x ? ptr21 : ptr12;
    int* cur = blockIdx.x ? cur21 : cur12;
    const int T = 1024, C = 10;                 // 1024*10 = 10240 >= 10000
    __shared__ int sm[1024];
    int t = threadIdx.x;
    int v[C]; int tot = 0;
    int base = t * C;
    #pragma unroll
    for (int i = 0; i < C; i++) {
        int id = base + i;
        v[i] = (id < NN) ? cnt[id] : 0;
        tot += v[i];
    }
    sm[t] = tot; __syncthreads();
    for (int off = 1; off < T; off <<= 1) {
        int x = (t >= off) ? sm[t - off] : 0;
        __syncthreads();
        sm[t] += x;
        __syncthreads();
    }
    int run = sm[t] - tot;                      // exclusive prefix
    #pragma unroll
    for (int i = 0; i < C; i++) {
        int id = base + i;
        if (id < NN) { ptr[id] = run; cur[id] = run; }
        run += v[i];
    }
    if (t == T - 1) ptr[NN] = run;
}

// writes rows_sorted (source row per CSR slot; dest is implicit in slot range)
__global__ void fill_kernel(const int* e12, const int* e21,
                            int* cur12, int* cur21, int* rs12, int* rs21) {
    int t = blockIdx.x * blockDim.x + threadIdx.x;
    if (t < NE) {
        int c = e12[NE + t];
        int p = atomicAdd(&cur12[c], 1);
        rs12[p] = e12[t];
    } else if (t < 2 * NE) {
        int e = t - NE;
        int c = e21[NE + e];
        int p = atomicAdd(&cur21[c], 1);
        rs21[p] = e21[e];
    }
}

// ---------------- shared device pieces ----------------

__device__ __forceinline__ float dotc(const uint4& k, const uint4& q) {
#if __has_builtin(__builtin_amdgcn_fdot2)
    const h2v* kh = (const h2v*)&k;
    const h2v* qh = (const h2v*)&q;
    float s = 0.f;
    #pragma unroll
    for (int i = 0; i < 4; i++)
        s = __builtin_amdgcn_fdot2(kh[i], qh[i], s, false);
    return s;
#else
    const __half2* kh = (const __half2*)&k;
    const __half2* qh = (const __half2*)&q;
    float s = 0.f;
    #pragma unroll
    for (int i = 0; i < 4; i++) {
        float2 a = __half22float2(kh[i]);
        float2 b = __half22float2(qh[i]);
        s += a.x * b.x + a.y * b.y;
    }
    return s;
#endif
}
__device__ __forceinline__ void acc8(const uint4& v, float e, float* acc) {
    const __half2* h = (const __half2*)&v;
    float2 f0 = __half22float2(h[0]), f1 = __half22float2(h[1]);
    float2 f2 = __half22float2(h[2]), f3 = __half22float2(h[3]);
    acc[0] += e*f0.x; acc[1] += e*f0.y; acc[2] += e*f1.x; acc[3] += e*f1.y;
    acc[4] += e*f2.x; acc[5] += e*f2.y; acc[6] += e*f3.x; acc[7] += e*f3.y;
}

// 3 K/Q/V GEMM phases over the block's 16 x-rows held in LDS (Xs, 16x64 f32).
// node type z: K,V -> rel=z ; Q -> rel=1-z. W staged in Ws (32 KB) per phase.
__device__ __forceinline__ void kqv_phases(
        int z, int l, const float* Xs, float4* Ws4, int row0, int tid,
        const float* __restrict__ Wk, const float* __restrict__ Wq,
        const float* __restrict__ Wv,
        const float* __restrict__ bk, const float* __restrict__ bq,
        const float* __restrict__ bv,
        __half* Kh, __half* Qh, __half* Vh) {
    #pragma unroll
    for (int kind = 0; kind < 3; kind++) {
        int rel = (kind == 1) ? (1 - z) : z;
        size_t wo = (size_t)(l * 2 + rel) * HD * HH;
        size_t bo = (size_t)(l * 2 + rel) * HH;
        const float4* W4 = (const float4*)((kind == 0 ? Wk : kind == 1 ? Wq : Wv) + wo);
        const float4* b4 = (const float4*)((kind == 0 ? bk : kind == 1 ? bq : bv) + bo);
        #pragma unroll
        for (int i = 0; i < 8; i++) Ws4[tid + 256 * i] = W4[tid + 256 * i];
        __syncthreads();
        int cg = tid & 31, rg = tid >> 5;       // rg 0..7, rows rg*2, rg*2+1
        float4 acc0 = b4[cg], acc1 = acc0;
        const float* a0 = &Xs[(rg * 2) * HD];
        const float* a1 = &Xs[(rg * 2 + 1) * HD];
        for (int k = 0; k < HD; k++) {
            float4 w = Ws4[k * 32 + cg];
            float v0 = a0[k], v1 = a1[k];
            acc0.x += v0 * w.x; acc0.y += v0 * w.y; acc0.z += v0 * w.z; acc0.w += v0 * w.w;
            acc1.x += v1 * w.x; acc1.y += v1 * w.y; acc1.z += v1 * w.z; acc1.w += v1 * w.w;
        }
        __half* dst = (kind == 0) ? Kh : (kind == 1) ? Qh : Vh;
        int node = row0 + rg * 2;
        {
            __half2* H2 = (__half2*)(dst + (size_t)rel * NN * HH + (size_t)node * HH + cg * 4);
            float2 lo = {acc0.x, acc0.y}, hi = {acc0.z, acc0.w};
            H2[0] = __float22half2_rn(lo);
            H2[1] = __float22half2_rn(hi);
        }
        {
            __half2* H2 = (__half2*)(dst + (size_t)rel * NN * HH + (size_t)(node + 1) * HH + cg * 4);
            float2 lo = {acc1.x, acc1.y}, hi = {acc1.z, acc1.w};
            H2[0] = __float22half2_rn(lo);
            H2[1] = __float22half2_rn(hi);
        }
        __syncthreads();                        // Ws reads done before next staging
    }
}

// ---------------- fused: input GEMM + layer-0 K/Q/V ----------------
__global__ __launch_bounds__(256) void in_kqv(
        const float* __restrict__ xn1, const float* __restrict__ xn2,
        const float* __restrict__ Win, const float* __restrict__ b_in,
        const float* __restrict__ Wk, const float* __restrict__ Wq,
        const float* __restrict__ Wv,
        const float* __restrict__ bk, const float* __restrict__ bq,
        const float* __restrict__ bv,
        __half* Kh, __half* Qh, __half* Vh) {
    int z = blockIdx.z;
    int tid = threadIdx.x;
    int row0 = blockIdx.x * 16;
    __shared__ float As[16 * DIN];              // 8 KB
    __shared__ float Ws[DIN * HD];              // 32 KB
    __shared__ float Xs[16 * HD];               // 4 KB
    float4* As4 = (float4*)As;
    float4* Ws4 = (float4*)Ws;
    float4* Xs4 = (float4*)Xs;
    {
        const float4* A4 = (const float4*)(z ? xn2 : xn1);
        const float4* W4 = (const float4*)(Win + (size_t)z * DIN * HD);
        const float4* b4 = (const float4*)(b_in + (size_t)z * HD);
        As4[tid]       = A4[(size_t)row0 * 32 + tid];
        As4[tid + 256] = A4[(size_t)row0 * 32 + tid + 256];
        #pragma unroll
        for (int i = 0; i < 8; i++) Ws4[tid + 256 * i] = W4[tid + 256 * i];
        __syncthreads();
        int r = tid >> 4, cg = tid & 15;
        float4 acc = b4[cg];
        const float* a = &As[r * DIN];
        for (int k = 0; k < DIN; k++) {
            float av = a[k];
            float4 w = Ws4[k * 16 + cg];
            acc.x += av * w.x; acc.y += av * w.y; acc.z += av * w.z; acc.w += av * w.w;
        }
        acc.x = fmaxf(acc.x, 0.f); acc.y = fmaxf(acc.y, 0.f);
        acc.z = fmaxf(acc.z, 0.f); acc.w = fmaxf(acc.w, 0.f);
        Xs4[r * 16 + cg] = acc;
        __syncthreads();
    }
    kqv_phases(z, 0, Xs, Ws4, row0, tid, Wk, Wq, Wv, bk, bq, bv, Kh, Qh, Vh);
}

// ---------------- fused: out GEMM (layer l) + K/Q/V (layer l+1) ----------------
__global__ __launch_bounds__(256) void out_kqv(
        const float* __restrict__ aggb,
        const float* __restrict__ Wout, const float* __restrict__ bout,
        const float* __restrict__ sums, int l,
        const float* __restrict__ Wk, const float* __restrict__ Wq,
        const float* __restrict__ Wv,
        const float* __restrict__ bk, const float* __restrict__ bq,
        const float* __restrict__ bv,
        __half* Kh, __half* Qh, __half* Vh,
        __half2* Emh2, __half2* Edh2) {
    int z = blockIdx.z;
    int sel = z ? 0 : 1;                        // which relation's aggregate
    int tid = threadIdx.x;
    int row0 = blockIdx.x * 16;
    __shared__ float As[16 * HH];               // 8 KB
    __shared__ float Ws[HH * HD];               // 32 KB
    __shared__ float Xs[16 * HD];               // 4 KB
    __shared__ float invs[2];
    float4* As4 = (float4*)As;
    float4* Ws4 = (float4*)Ws;
    float4* Xs4 = (float4*)Xs;
    {
        const float4* A4 = (const float4*)(aggb + (size_t)sel * NN * HH);
        const float4* W4 = (const float4*)(Wout + (size_t)(l * 2 + z) * HH * HD);
        const float4* b4 = (const float4*)(bout + (size_t)(l * 2 + z) * HD);
        __half2* E2 = z ? Edh2 : Emh2;
        if (tid < 128) {
            int h = tid >> 6;
            float v = sums[l * 256 + sel * 128 + h * 64 + (tid & 63)];
            #pragma unroll
            for (int off = 1; off <= 32; off <<= 1) v += __shfl_xor(v, off);
            if ((tid & 63) == 0) invs[h] = 1.f / v;
        }
        __syncthreads();
        float inv0 = invs[0], inv1 = invs[1];
        {
            float4 t0 = A4[(size_t)row0 * 32 + tid];
            float4 t1 = A4[(size_t)row0 * 32 + tid + 256];
            float s0 = ((tid & 31) < 16) ? inv0 : inv1;   // cols 0-63 = head0
            t0.x *= s0; t0.y *= s0; t0.z *= s0; t0.w *= s0;
            t1.x *= s0; t1.y *= s0; t1.z *= s0; t1.w *= s0;
            As4[tid] = t0; As4[tid + 256] = t1;
        }
        #pragma unroll
        for (int i = 0; i < 8; i++) Ws4[tid + 256 * i] = W4[tid + 256 * i];
        __syncthreads();
        int r = tid >> 4, cg = tid & 15;
        float4 acc = b4[cg];
        const float* a = &As[r * HH];
        for (int k = 0; k < HH; k++) {
            float av = a[k];
            float4 w = Ws4[k * 16 + cg];
            acc.x += av * w.x; acc.y += av * w.y; acc.z += av * w.z; acc.w += av * w.w;
        }
        int node = row0 + r;
        Xs4[r * 16 + cg] = acc;
        float2 lo = {acc.x, acc.y}, hi = {acc.z, acc.w};
        E2[(size_t)node * 64 + l * 32 + cg * 2]     = __float22half2_rn(lo);
        E2[(size_t)node * 64 + l * 32 + cg * 2 + 1] = __float22half2_rn(hi);
        __syncthreads();
    }
    kqv_phases(z, l + 1, Xs, Ws4, row0, tid, Wk, Wq, Wv, bk, bq, bv, Kh, Qh, Vh);
}

// ---------------- final out GEMM (layer 1; Em/Ed only) ----------------
__global__ __launch_bounds__(256) void out_last(
        const float* __restrict__ aggb,
        const float* __restrict__ Wout, const float* __restrict__ bout,
        const float* __restrict__ sums, int l,
        __half2* Emh2, __half2* Edh2) {
    int z = blockIdx.z;
    int sel = z ? 0 : 1;
    const float4* A4 = (const float4*)(aggb + (size_t)sel * NN * HH);
    const float4* W4 = (const float4*)(Wout + (size_t)(l * 2 + z) * HH * HD);
    const float4* b4 = (const float4*)(bout + (size_t)(l * 2 + z) * HD);
    __half2* E2 = z ? Edh2 : Emh2;
    __shared__ float As[16 * HH];
    __shared__ float Ws[HH * HD];
    __shared__ float invs[2];
    int tid = threadIdx.x;
    if (tid < 128) {
        int h = tid >> 6;
        float v = sums[l * 256 + sel * 128 + h * 64 + (tid & 63)];
        #pragma unroll
        for (int off = 1; off <= 32; off <<= 1) v += __shfl_xor(v, off);
        if ((tid & 63) == 0) invs[h] = 1.f / v;
    }
    __syncthreads();
    float inv0 = invs[0], inv1 = invs[1];
    int row0 = blockIdx.x * 16;
    float4* As4 = (float4*)As;
    float4* Ws4 = (float4*)Ws;
    {
        float4 t0 = A4[(size_t)row0 * 32 + tid];
        float4 t1 = A4[(size_t)row0 * 32 + tid + 256];
        float s0 = ((tid & 31) < 16) ? inv0 : inv1;
        t0.x *= s0; t0.y *= s0; t0.z *= s0; t0.w *= s0;
        t1.x *= s0; t1.y *= s0; t1.z *= s0; t1.w *= s0;
        As4[tid] = t0; As4[tid + 256] = t1;
    }
    #pragma unroll
    for (int i = 0; i < 8; i++) Ws4[tid + 256 * i] = W4[tid + 256 * i];
    __syncthreads();
    int r = tid >> 4, cg = tid & 15;
    float4 acc = b4[cg];
    const float* a = &As[r * HH];
    for (int k = 0; k < HH; k++) {
        float av = a[k];
        float4 w = Ws4[k * 16 + cg];
        acc.x += av * w.x; acc.y += av * w.y; acc.z += av * w.z; acc.w += av * w.w;
    }
    int node = row0 + r;
    float2 lo = {acc.x, acc.y}, hi = {acc.z, acc.w};
    E2[(size_t)node * 64 + l * 32 + cg * 2]     = __float22half2_rn(lo);
    E2[(size_t)node * 64 + l * 32 + cg * 2 + 1] = __float22half2_rn(hi);
}

// ---------------- single-pass fused attention: block = (rel, 8 dest nodes) ----
// 8-lane group per edge, 2 edges per iteration. Q for the node is loop-invariant
// (CSR sorted by dest) -> hoisted: 4 global loads/edge instead of 6, and the
// edge table is a plain row array (half the index bytes).
__global__ __launch_bounds__(256) void conv_fused(
        const int* __restrict__ ptr12, const int* __restrict__ rs12,
        const int* __restrict__ ptr21, const int* __restrict__ rs21,
        const __half* __restrict__ Kh, const __half* __restrict__ Qh,
        const __half* __restrict__ Vh,
        float* __restrict__ aggb, float* __restrict__ sums, int l) {
    int b = blockIdx.x;
    int rel = b & 1, seg = b >> 1;              // seg in [0, 1250)
    const int* __restrict__ ptr = rel ? ptr21 : ptr12;
    const int* __restrict__ rs  = rel ? rs21 : rs12;
    const uint4* K = (const uint4*)(Kh + (size_t)rel * NN * HH);
    const uint4* Q = (const uint4*)(Qh + (size_t)rel * NN * HH);
    const uint4* V = (const uint4*)(Vh + (size_t)rel * NN * HH);
    float4* A4 = (float4*)(aggb + (size_t)rel * NN * HH);
    int tid = threadIdx.x;
    int wave = tid >> 6, lane = tid & 63;
    int g = lane >> 3, s8 = lane & 7;           // group 0..7, lane-in-group
    int c0 = seg * 8;
    float s0 = 0.f, s1 = 0.f;
    #pragma unroll
    for (int ni = 0; ni < 2; ni++) {
        int c = c0 + wave * 2 + ni;
        int jb = ptr[c], je = ptr[c + 1];
        uint4 q0 = Q[(size_t)c * 16 + s8];      // hoisted: dest is fixed per node
        uint4 q1 = Q[(size_t)c * 16 + 8 + s8];
        float accA[8] = {0,0,0,0,0,0,0,0};
        float accB[8] = {0,0,0,0,0,0,0,0};
        for (int j = jb + g; j < je; j += 16) {
            int rA = rs[j];
            int jB = j + 8;
            bool hB = jB < je;
            int rB = hB ? rs[jB] : 0;
            const uint4* kpA = K + (size_t)rA * 16;
            const uint4* vpA = V + (size_t)rA * 16;
            const uint4* kpB = K + (size_t)rB * 16;
            const uint4* vpB = V + (size_t)rB * 16;
            uint4 kA0 = kpA[s8],     vA0 = vpA[s8];
            uint4 kA1 = kpA[8 + s8], vA1 = vpA[8 + s8];
            uint4 kB0 = kpB[s8],     vB0 = vpB[s8];
            uint4 kB1 = kpB[8 + s8], vB1 = vpB[8 + s8];
            float pA0 = dotc(kA0, q0), pA1 = dotc(kA1, q1);
            float pB0 = dotc(kB0, q0), pB1 = dotc(kB1, q1);
            #pragma unroll
            for (int off = 1; off <= 4; off <<= 1) {   // butterfly within 8 lanes
                pA0 += __shfl_xor(pA0, off);
                pA1 += __shfl_xor(pA1, off);
                pB0 += __shfl_xor(pB0, off);
                pB1 += __shfl_xor(pB1, off);
            }
            pA0 *= 0.125f; pA1 *= 0.125f; pB0 *= 0.125f; pB1 *= 0.125f;
            pA0 = pA0 > 0.f ? pA0 : 0.2f * pA0;
            pA1 = pA1 > 0.f ? pA1 : 0.2f * pA1;
            pB0 = pB0 > 0.f ? pB0 : 0.2f * pB0;
            pB1 = pB1 > 0.f ? pB1 : 0.2f * pB1;
            float eA0 = __expf(pA0), eA1 = __expf(pA1);
            float eB0 = hB ? __expf(pB0) : 0.f;
            float eB1 = hB ? __expf(pB1) : 0.f;
            acc8(vA0, eA0, accA);
            acc8(vA1, eA1, accB);
            acc8(vB0, eB0, accA);
            acc8(vB1, eB1, accB);
            if (s8 == 0) { s0 += eA0; s0 += eB0; s1 += eA1; s1 += eB1; }
        }
        // cross-group reduce (groups hold disjoint edge subsets of this node)
        #pragma unroll
        for (int i = 0; i < 8; i++) {
            accA[i] += __shfl_xor(accA[i], 8);
            accA[i] += __shfl_xor(accA[i], 16);
            accA[i] += __shfl_xor(accA[i], 32);
            accB[i] += __shfl_xor(accB[i], 8);
            accB[i] += __shfl_xor(accB[i], 16);
            accB[i] += __shfl_xor(accB[i], 32);
        }
        if (g == 0) {                           // lanes 0..7 write the full row
            float4 a0 = {accA[0], accA[1], accA[2], accA[3]};
            float4 a1 = {accA[4], accA[5], accA[6], accA[7]};
            float4 b0 = {accB[0], accB[1], accB[2], accB[3]};
            float4 b1 = {accB[4], accB[5], accB[6], accB[7]};
            A4[(size_t)c * 32 + 2 * s8]          = a0;
            A4[(size_t)c * 32 + 2 * s8 + 1]      = a1;
            A4[(size_t)c * 32 + 16 + 2 * s8]     = b0;
            A4[(size_t)c * 32 + 16 + 2 * s8 + 1] = b1;
        }
    }
    // exp-sum: only s8==0 lanes nonzero -> butterfly over group bits
    s0 += __shfl_xor(s0, 8);  s0 += __shfl_xor(s0, 16); s0 += __shfl_xor(s0, 32);
    s1 += __shfl_xor(s1, 8);  s1 += __shfl_xor(s1, 16); s1 += __shfl_xor(s1, 32);
    __shared__ float sred[4][2];
    if (lane == 0) { sred[wave][0] = s0; sred[wave][1] = s1; }
    __syncthreads();
    if (tid < 2) {
        float t = sred[0][tid] + sred[1][tid] + sred[2][tid] + sred[3][tid];
        atomicAdd(&sums[l * 256 + rel * 128 + tid * 64 + (seg & 63)], t);
    }
}

// ---------------- prediction (8-lane group per pair, fdot2) ----------------
__global__ __launch_bounds__(256) void pred_kernel(
        const __half* __restrict__ Emh, const __half* __restrict__ Edh,
        const int* __restrict__ pe, float* out) {
    int grp = (blockIdx.x * 256 + threadIdx.x) >> 3;   // pair index
    int s8 = threadIdx.x & 7;
    if (grp >= NP) return;
    int m = pe[grp], d = pe[NP + grp];
    const uint4* a = (const uint4*)Emh + (size_t)m * 16;
    const uint4* b = (const uint4*)Edh + (size_t)d * 16;
    float acc = dotc(a[s8], b[s8]) + dotc(a[8 + s8], b[8 + s8]);
    #pragma unroll
    for (int off = 1; off <= 4; off <<= 1) acc += __shfl_xor(acc, off);
    if (s8 == 0) out[grp] = acc;
}

// ---------------- host ----------------

extern "C" void kernel_launch(void* const* d_in, const int* in_sizes, int n_in,
                              void* d_out, int out_size, void* d_ws, size_t ws_size,
                              hipStream_t stream) {
    (void)in_sizes; (void)n_in; (void)out_size; (void)ws_size;
    const float* x_n1 = (const float*)d_in[0];
    const float* x_n2 = (const float*)d_in[1];
    const int*   e12  = (const int*)d_in[2];
    const int*   e21  = (const int*)d_in[3];
    const int*   pe   = (const int*)d_in[4];
    const float* Win  = (const float*)d_in[5];
    const float* b_in = (const float*)d_in[6];
    const float* Wk   = (const float*)d_in[7];
    const float* bk   = (const float*)d_in[8];
    const float* Wq   = (const float*)d_in[9];
    const float* bq   = (const float*)d_in[10];
    const float* Wv   = (const float*)d_in[11];
    const float* bv   = (const float*)d_in[12];
    const float* Wout = (const float*)d_in[13];
    const float* bout = (const float*)d_in[14];
    float* out = (float*)d_out;

    char* w = (char*)d_ws;
    auto carve = [&](size_t nbytes) -> void* {
        void* p = (void*)w;
        w += (nbytes + 255) & ~(size_t)255;
        return p;
    };
    __half* Kh   = (__half*)carve((size_t)2 * NN * HH * 2);
    __half* Qh   = (__half*)carve((size_t)2 * NN * HH * 2);
    __half* Vh   = (__half*)carve((size_t)2 * NN * HH * 2);
    float* aggb  = (float*)carve((size_t)2 * NN * HH * 4);
    __half2* Emh2 = (__half2*)carve((size_t)NN * HH * 2);
    __half2* Edh2 = (__half2*)carve((size_t)NN * HH * 2);
    int* cnt     = (int*)carve((size_t)2 * NN * 4);    // cnt + sums: one memset
    float* sums  = (float*)carve((size_t)2 * 256 * 4);
    int* cur12   = (int*)carve((size_t)NN * 4);
    int* cur21   = (int*)carve((size_t)NN * 4);
    int* ptr12   = (int*)carve((size_t)(NN + 1) * 4);
    int* ptr21   = (int*)carve((size_t)(NN + 1) * 4);
    int* rs12    = (int*)carve((size_t)NE * 4);
    int* rs21    = (int*)carve((size_t)NE * 4);
    int* cnt12 = cnt;
    int* cnt21 = cnt + NN;

    // zero cnt + sums (adjacent carves) in one memset
    size_t zbytes = (((size_t)2 * NN * 4 + 255) & ~(size_t)255) + (size_t)2 * 256 * 4;
    hipMemsetAsync(cnt, 0, zbytes, stream);

    // CSR build
    int eb = (2 * NE + 255) / 256;
    count_kernel<<<(NE / 2 + 255) / 256, 256, 0, stream>>>(e12, e21, cnt12, cnt21);
    scan_kernel<<<2, 1024, 0, stream>>>(cnt12, cnt21, ptr12, ptr21, cur12, cur21);
    fill_kernel<<<eb, 256, 0, stream>>>(e12, e21, cur12, cur21, rs12, rs21);

    // input linear + relu fused with layer-0 K/Q/V (x lives only in LDS)
    in_kqv<<<dim3(NN / 16, 1, 2), 256, 0, stream>>>(
        x_n1, x_n2, Win, b_in, Wk, Wq, Wv, bk, bq, bv, Kh, Qh, Vh);

    conv_fused<<<dim3(NN / 8 * 2), 256, 0, stream>>>(
        ptr12, rs12, ptr21, rs21, Kh, Qh, Vh, aggb, sums, 0);

    // out GEMM layer 0 fused with layer-1 K/Q/V
    out_kqv<<<dim3(NN / 16, 1, 2), 256, 0, stream>>>(
        aggb, Wout, bout, sums, 0, Wk, Wq, Wv, bk, bq, bv, Kh, Qh, Vh, Emh2, Edh2);

    conv_fused<<<dim3(NN / 8 * 2), 256, 0, stream>>>(
        ptr12, rs12, ptr21, rs21, Kh, Qh, Vh, aggb, sums, 1);

    out_last<<<dim3(NN / 16, 1, 2), 256, 0, stream>>>(
        aggb, Wout, bout, sums, 1, Emh2, Edh2);

    pred_kernel<<<(NP * 8 + 255) / 256, 256, 0, stream>>>(
        (const __half*)Emh2, (const __half*)Edh2, pe, out);
}